// Round 6
// baseline (3337.398 us; speedup 1.0000x reference)
//
#include <hip/hip_runtime.h>
#include <hip/hip_bf16.h>

// Problem constants
#define BATCH   64
#define SEQ     512
#define IN0     512
#define HID     128
#define G3      384   // 3*HID
#define NLAY    5

typedef _Float16 f16x8 __attribute__((ext_vector_type(8)));
typedef float    f32x4 __attribute__((ext_vector_type(4)));

// ---------------------------------------------------------------------------
// gemm_gx: gx[M=32768][384] = A[M][K] @ W[384][K]^T + bias[384]   (all fp32)
// Tile 64(M) x 64(N), block 256 threads, 4x4 microtile, K-step 32. (unchanged)
// ---------------------------------------------------------------------------
__global__ __launch_bounds__(256) void gemm_gx(const float* __restrict__ A,
                                               const float* __restrict__ W,
                                               const float* __restrict__ bias,
                                               float* __restrict__ gx,
                                               int K)
{
    __shared__ __align__(16) float As[32][68];
    __shared__ __align__(16) float Bs[32][68];

    const int row0 = blockIdx.x * 64;
    const int col0 = blockIdx.y * 64;
    const int tid  = threadIdx.x;
    const int tx   = tid & 15;
    const int ty   = tid >> 4;
    const int r    = tid >> 2;
    const int kc   = (tid & 3) * 8;

    float acc[4][4] = {};

    for (int k0 = 0; k0 < K; k0 += 32) {
        {
            const float* Ap = A + (size_t)(row0 + r) * K + k0 + kc;
            float4 a0 = *(const float4*)(Ap);
            float4 a1 = *(const float4*)(Ap + 4);
            As[kc + 0][r] = a0.x; As[kc + 1][r] = a0.y; As[kc + 2][r] = a0.z; As[kc + 3][r] = a0.w;
            As[kc + 4][r] = a1.x; As[kc + 5][r] = a1.y; As[kc + 6][r] = a1.z; As[kc + 7][r] = a1.w;
        }
        {
            const float* Wp = W + (size_t)(col0 + r) * K + k0 + kc;
            float4 b0 = *(const float4*)(Wp);
            float4 b1 = *(const float4*)(Wp + 4);
            Bs[kc + 0][r] = b0.x; Bs[kc + 1][r] = b0.y; Bs[kc + 2][r] = b0.z; Bs[kc + 3][r] = b0.w;
            Bs[kc + 4][r] = b1.x; Bs[kc + 5][r] = b1.y; Bs[kc + 6][r] = b1.z; Bs[kc + 7][r] = b1.w;
        }
        __syncthreads();

        #pragma unroll
        for (int kk = 0; kk < 32; kk++) {
            float4 a = *(const float4*)&As[kk][ty * 4];
            float4 b = *(const float4*)&Bs[kk][tx * 4];
            acc[0][0] = fmaf(a.x, b.x, acc[0][0]); acc[0][1] = fmaf(a.x, b.y, acc[0][1]);
            acc[0][2] = fmaf(a.x, b.z, acc[0][2]); acc[0][3] = fmaf(a.x, b.w, acc[0][3]);
            acc[1][0] = fmaf(a.y, b.x, acc[1][0]); acc[1][1] = fmaf(a.y, b.y, acc[1][1]);
            acc[1][2] = fmaf(a.y, b.z, acc[1][2]); acc[1][3] = fmaf(a.y, b.w, acc[1][3]);
            acc[2][0] = fmaf(a.z, b.x, acc[2][0]); acc[2][1] = fmaf(a.z, b.y, acc[2][1]);
            acc[2][2] = fmaf(a.z, b.z, acc[2][2]); acc[2][3] = fmaf(a.z, b.w, acc[2][3]);
            acc[3][0] = fmaf(a.w, b.x, acc[3][0]); acc[3][1] = fmaf(a.w, b.y, acc[3][1]);
            acc[3][2] = fmaf(a.w, b.z, acc[3][2]); acc[3][3] = fmaf(a.w, b.w, acc[3][3]);
        }
        __syncthreads();
    }

    float bb[4];
    #pragma unroll
    for (int j = 0; j < 4; j++) bb[j] = bias[col0 + tx * 4 + j];
    #pragma unroll
    for (int i = 0; i < 4; i++) {
        const int row = row0 + ty * 4 + i;
        float4 v;
        v.x = acc[i][0] + bb[0];
        v.y = acc[i][1] + bb[1];
        v.z = acc[i][2] + bb[2];
        v.w = acc[i][3] + bb[3];
        *(float4*)&gx[(size_t)row * G3 + col0 + tx * 4] = v;
    }
}

// ---------------------------------------------------------------------------
// mfma_scan: batched-MFMA GRU scan. Block g handles batches [16g, 16g+16).
// Per step: hh[16m][384n] = h_f16[16][128] @ W_hh_f16^T via 12 x
// v_mfma_f32_16x16x32_f16 per wave (fp32 accumulate).
//   wave wv (0..7): j-slice jw = 16*wv; owns B-frags for n in
//     {jw..jw+16} + {0,128,256}  (r,z,n gate rows for the same j's).
//   lane: n16 = lane&15 (j offset / MFMA col), quad = lane>>4.
//   A-frag (shared by waves): A[m=lane&15][k=quad*8+i], read from LDS
//     hA[2][16][136] f16 (pad 136 -> conflict-free b128 reads).
//   C-layout: col(n)=lane&15, row(m)=quad*4+reg -> lane owns 4 batches x 1 j
//     for all three gates => gate finalize fully in-registers, no LDS.
//   h feedback: lane computed h[m][j] last step (same mapping) -> kept in
//     vhp[4]; also written to hA for the next step's A-frags. ONE barrier.
//   gx: read per-lane from global (quad-coalesced 64B lines), register-
//     prefetched one step ahead.
// ---------------------------------------------------------------------------
__global__ __launch_bounds__(512, 2) void mfma_scan(const float* __restrict__ gx,   // [BATCH][SEQ][384]
                                                    const float* __restrict__ w_hh, // [384][128] layer slice
                                                    const float* __restrict__ b_hh, // [384] layer slice
                                                    float* __restrict__ hseq)       // [BATCH][SEQ][128]
{
    const int g    = blockIdx.x;        // batch group
    const int bm0  = g * 16;
    const int tid  = threadIdx.x;
    const int lane = tid & 63;
    const int wv   = tid >> 6;
    const int n16  = lane & 15;
    const int quad = lane >> 4;
    const int jw   = wv * 16;
    const int j    = jw + n16;          // hidden index this lane finalizes

    __shared__ __align__(16) _Float16 hA[2][16][136];

    // ---- B fragments: bf[gate][kc] = W[n][kc*32 + quad*8 + i], n = gate*128+j
    f16x8 bf[3][4];
    #pragma unroll
    for (int tau = 0; tau < 3; tau++) {
        const int n = tau * 128 + j;
        #pragma unroll
        for (int kc = 0; kc < 4; kc++) {
            const float* wp = w_hh + (size_t)n * HID + kc * 32 + quad * 8;
            f16x8 v;
            #pragma unroll
            for (int i = 0; i < 8; i++) v[i] = (_Float16)wp[i];
            bf[tau][kc] = v;
        }
    }
    const float bhr = b_hh[j];
    const float bhz = b_hh[j + 128];
    const float bhn = b_hh[j + 256];

    // ---- zero h state ----
    for (int i = tid; i < 2 * 16 * 136; i += 512) ((_Float16*)hA)[i] = (_Float16)0.f;
    float vhp[4] = {0.f, 0.f, 0.f, 0.f};

    // ---- gx pointers: 4 batch rows (m = quad*4 + r), gate offsets +0/+128/+256
    const float* pR[4];
    float*       hp[4];
    #pragma unroll
    for (int r = 0; r < 4; r++) {
        const int b = bm0 + quad * 4 + r;
        pR[r] = gx   + (size_t)b * SEQ * G3 + j;
        hp[r] = hseq + (size_t)b * SEQ * HID + j;
    }

    // preload gx for t=0
    float xr[4], xz[4], xn[4];
    #pragma unroll
    for (int r = 0; r < 4; r++) {
        xr[r] = pR[r][0]; xz[r] = pR[r][128]; xn[r] = pR[r][256];
        pR[r] += G3;
    }

    __syncthreads();

    for (int t = 0; t < SEQ; t++) {
        // prefetch gx for t+1 (in flight across this step)
        float nr[4], nz[4], nn[4];
        #pragma unroll
        for (int r = 0; r < 4; r++) {
            nr[r] = pR[r][0]; nz[r] = pR[r][128]; nn[r] = pR[r][256];
        }
        if (t + 1 < SEQ) {
            #pragma unroll
            for (int r = 0; r < 4; r++) pR[r] += G3;
        }

        const int buf = t & 1;
        // A fragments (shared across waves)
        f16x8 af[4];
        #pragma unroll
        for (int kc = 0; kc < 4; kc++)
            af[kc] = *(const f16x8*)&hA[buf][n16][kc * 32 + quad * 8];

        // 12 MFMA: 3 gate-tiles x 4 k-chunks
        f32x4 acc[3];
        #pragma unroll
        for (int tau = 0; tau < 3; tau++) acc[tau] = (f32x4){0.f, 0.f, 0.f, 0.f};
        #pragma unroll
        for (int kc = 0; kc < 4; kc++) {
            acc[0] = __builtin_amdgcn_mfma_f32_16x16x32_f16(af[kc], bf[0][kc], acc[0], 0, 0, 0);
            acc[1] = __builtin_amdgcn_mfma_f32_16x16x32_f16(af[kc], bf[1][kc], acc[1], 0, 0, 0);
            acc[2] = __builtin_amdgcn_mfma_f32_16x16x32_f16(af[kc], bf[2][kc], acc[2], 0, 0, 0);
        }

        // gates: lane owns (m = quad*4 + r, j); acc[tau][r] = hh pre-act
        const int nbuf = buf ^ 1;
        #pragma unroll
        for (int r = 0; r < 4; r++) {
            const float ghr = acc[0][r] + bhr;
            const float ghz = acc[1][r] + bhz;
            const float ghn = acc[2][r] + bhn;
            const float rg  = 1.f / (1.f + __expf(-(xr[r] + ghr)));
            const float zg  = 1.f / (1.f + __expf(-(xz[r] + ghz)));
            const float pre = xn[r] + rg * ghn;
            const float e   = __expf(-2.f * fabsf(pre));
            const float th  = copysignf((1.f - e) / (1.f + e), pre);   // tanh
            const float hnew = fmaf(zg, vhp[r] - th, th);              // (1-z)n + z h
            vhp[r] = hnew;
            hA[nbuf][quad * 4 + r][j] = (_Float16)hnew;
            hp[r][(size_t)t * HID] = hnew;
        }
        __syncthreads();

        #pragma unroll
        for (int r = 0; r < 4; r++) { xr[r] = nr[r]; xz[r] = nz[r]; xn[r] = nn[r]; }
    }
}

// ---------------------------------------------------------------------------
// fc: out[b][o] = hseq[b][T-1][:] . fc_w[o][:] + fc_b[o]
// ---------------------------------------------------------------------------
__global__ __launch_bounds__(128) void fc_kernel(const float* __restrict__ hseq,
                                                 const float* __restrict__ fc_w,
                                                 const float* __restrict__ fc_b,
                                                 float* __restrict__ out)
{
    const int b = blockIdx.x;
    const int o = threadIdx.x;
    if (o < 96) {
        const float* h = hseq + (size_t)b * (SEQ * HID) + (size_t)(SEQ - 1) * HID;
        const float* wrow = fc_w + o * HID;
        float acc = fc_b[o];
        #pragma unroll 4
        for (int k = 0; k < HID; k++) acc = fmaf(h[k], wrow[k], acc);
        out[b * 96 + o] = acc;
    }
}

// ---------------------------------------------------------------------------
extern "C" void kernel_launch(void* const* d_in, const int* in_sizes, int n_in,
                              void* d_out, int out_size, void* d_ws, size_t ws_size,
                              hipStream_t stream)
{
    const float* x         = (const float*)d_in[0]; // [64][512][512]
    const float* w_ih0     = (const float*)d_in[1]; // [384][512]
    const float* w_ih_rest = (const float*)d_in[2]; // [4][384][128]
    const float* w_hh      = (const float*)d_in[3]; // [5][384][128]
    const float* b_ih      = (const float*)d_in[4]; // [5][384]
    const float* b_hh      = (const float*)d_in[5]; // [5][384]
    const float* fc_w      = (const float*)d_in[6]; // [96][128]
    const float* fc_b      = (const float*)d_in[7]; // [96]
    float* out = (float*)d_out;                     // [64][96]

    float* gxbuf = (float*)d_ws;                    // 32768*384 fp32 = 50.3 MB
    float* hseq  = gxbuf + (size_t)32768 * G3;      // 32768*128 fp32 = 16.8 MB

    const dim3 gemmGrid(512, 6);

    gemm_gx<<<gemmGrid, 256, 0, stream>>>(x, w_ih0, b_ih, gxbuf, IN0);
    mfma_scan<<<4, 512, 0, stream>>>(gxbuf, w_hh, b_hh, hseq);

    for (int l = 1; l < NLAY; l++) {
        gemm_gx<<<gemmGrid, 256, 0, stream>>>(hseq,
                                              w_ih_rest + (size_t)(l - 1) * G3 * HID,
                                              b_ih + (size_t)l * G3,
                                              gxbuf, HID);
        mfma_scan<<<4, 512, 0, stream>>>(gxbuf,
                                         w_hh + (size_t)l * G3 * HID,
                                         b_hh + (size_t)l * G3,
                                         hseq);
    }

    fc_kernel<<<BATCH, 128, 0, stream>>>(hseq, fc_w, fc_b, out);
}

// Round 7
// 1804.408 us; speedup vs baseline: 1.8496x; 1.8496x over previous
//
#include <hip/hip_runtime.h>
#include <hip/hip_bf16.h>

// Problem constants
#define BATCH   64
#define SEQ     512
#define IN0     512
#define HID     128
#define G3      384   // 3*HID
#define NLAY    5

typedef _Float16 f16x8 __attribute__((ext_vector_type(8)));
typedef float    f32x4 __attribute__((ext_vector_type(4)));

static __device__ __forceinline__ float sigf(float x) {
    // approx rcp (v_rcp_f32, ~1 ulp) instead of precise-divide sequence
    return __builtin_amdgcn_rcpf(1.f + __expf(-x));
}
static __device__ __forceinline__ float tanh_fast(float x) {
    const float e = __expf(-2.f * fabsf(x));
    return copysignf((1.f - e) * __builtin_amdgcn_rcpf(1.f + e), x);
}

// ---------------------------------------------------------------------------
// gemm_gx: gx0[M=32768][384] = x[M][512] @ w_ih0[384][512]^T + b_ih0  (fp32)
// Tile 64x64, 256 threads, 4x4 microtile, K-step 32.  (layer 0 only)
// ---------------------------------------------------------------------------
__global__ __launch_bounds__(256) void gemm_gx(const float* __restrict__ A,
                                               const float* __restrict__ W,
                                               const float* __restrict__ bias,
                                               float* __restrict__ gx,
                                               int K)
{
    __shared__ __align__(16) float As[32][68];
    __shared__ __align__(16) float Bs[32][68];

    const int row0 = blockIdx.x * 64;
    const int col0 = blockIdx.y * 64;
    const int tid  = threadIdx.x;
    const int tx   = tid & 15;
    const int ty   = tid >> 4;
    const int r    = tid >> 2;
    const int kc   = (tid & 3) * 8;

    float acc[4][4] = {};

    for (int k0 = 0; k0 < K; k0 += 32) {
        {
            const float* Ap = A + (size_t)(row0 + r) * K + k0 + kc;
            float4 a0 = *(const float4*)(Ap);
            float4 a1 = *(const float4*)(Ap + 4);
            As[kc + 0][r] = a0.x; As[kc + 1][r] = a0.y; As[kc + 2][r] = a0.z; As[kc + 3][r] = a0.w;
            As[kc + 4][r] = a1.x; As[kc + 5][r] = a1.y; As[kc + 6][r] = a1.z; As[kc + 7][r] = a1.w;
        }
        {
            const float* Wp = W + (size_t)(col0 + r) * K + k0 + kc;
            float4 b0 = *(const float4*)(Wp);
            float4 b1 = *(const float4*)(Wp + 4);
            Bs[kc + 0][r] = b0.x; Bs[kc + 1][r] = b0.y; Bs[kc + 2][r] = b0.z; Bs[kc + 3][r] = b0.w;
            Bs[kc + 4][r] = b1.x; Bs[kc + 5][r] = b1.y; Bs[kc + 6][r] = b1.z; Bs[kc + 7][r] = b1.w;
        }
        __syncthreads();

        #pragma unroll
        for (int kk = 0; kk < 32; kk++) {
            float4 a = *(const float4*)&As[kk][ty * 4];
            float4 b = *(const float4*)&Bs[kk][tx * 4];
            acc[0][0] = fmaf(a.x, b.x, acc[0][0]); acc[0][1] = fmaf(a.x, b.y, acc[0][1]);
            acc[0][2] = fmaf(a.x, b.z, acc[0][2]); acc[0][3] = fmaf(a.x, b.w, acc[0][3]);
            acc[1][0] = fmaf(a.y, b.x, acc[1][0]); acc[1][1] = fmaf(a.y, b.y, acc[1][1]);
            acc[1][2] = fmaf(a.y, b.z, acc[1][2]); acc[1][3] = fmaf(a.y, b.w, acc[1][3]);
            acc[2][0] = fmaf(a.z, b.x, acc[2][0]); acc[2][1] = fmaf(a.z, b.y, acc[2][1]);
            acc[2][2] = fmaf(a.z, b.z, acc[2][2]); acc[2][3] = fmaf(a.z, b.w, acc[2][3]);
            acc[3][0] = fmaf(a.w, b.x, acc[3][0]); acc[3][1] = fmaf(a.w, b.y, acc[3][1]);
            acc[3][2] = fmaf(a.w, b.z, acc[3][2]); acc[3][3] = fmaf(a.w, b.w, acc[3][3]);
        }
        __syncthreads();
    }

    float bb[4];
    #pragma unroll
    for (int jj = 0; jj < 4; jj++) bb[jj] = bias[col0 + tx * 4 + jj];
    #pragma unroll
    for (int i = 0; i < 4; i++) {
        const int row = row0 + ty * 4 + i;
        float4 v;
        v.x = acc[i][0] + bb[0];
        v.y = acc[i][1] + bb[1];
        v.z = acc[i][2] + bb[2];
        v.w = acc[i][3] + bb[3];
        *(float4*)&gx[(size_t)row * G3 + col0 + tx * 4] = v;
    }
}

// ---------------------------------------------------------------------------
// gru_pipeline: all 5 layers pipelined. 20 blocks = 5 layers x 4 batch-groups
// (all co-resident on 20 of 256 CUs -> persistent-kernel pipeline).
// Block (l,g): MFMA GRU scan for layer l, batches [16g,16g+16).
//   Layer 0:   gx from precomputed gx0 (fp32, bias included), reg-prefetched.
//   Layers>=1: gx computed on the fly: 12 extra mfma_f32_16x16x32_f16 with
//              A = h_prev(t) f16 frags (from hmid) and B = w_ih frags.
// Cross-layer handoff: hmid[l][g][t][16][128] f16 + flags[l*4+g] (#steps
// published). Producer: stores h(t) end of iter t; loop-top __syncthreads
// drains them (vmcnt0); tid0 release-stores flag=t (AGENT scope -> L2
// writeback, cross-XCD safe). Consumer: acquire-load flag at iter TOP,
// check at iter BOTTOM (latency overlapped), prefetch h_prev(t+1) frags
// for next iter -> steady-state lag 2 steps, handoff off critical path.
// ---------------------------------------------------------------------------
__global__ __launch_bounds__(512, 2) void gru_pipeline(
    const float* __restrict__ gx0,        // [64][512][384]
    const float* __restrict__ w_ih_rest,  // [4][384][128]
    const float* __restrict__ w_hh,       // [5][384][128]
    const float* __restrict__ b_ih,       // [5][384]
    const float* __restrict__ b_hh,       // [5][384]
    _Float16* __restrict__ hmid,          // [4][4][512][16][128]
    float* __restrict__ hlast,            // [64][128]
    int* __restrict__ flags)              // [16]
{
    const int l    = blockIdx.x >> 2;
    const int g    = blockIdx.x & 3;
    const int bm0  = g * 16;
    const int tid  = threadIdx.x;
    const int lane = tid & 63;
    const int wv   = tid >> 6;
    const int n16  = lane & 15;
    const int quad = lane >> 4;
    const int j    = wv * 16 + n16;       // hidden index this lane finalizes

    __shared__ __align__(16) _Float16 hA[2][16][136];

    // ---- B-frags for w_hh: bf[gate][kc] = W[gate*128+j][kc*32+quad*8+i]
    f16x8 bf[3][4];
    {
        const float* wb = w_hh + (size_t)l * G3 * HID;
        #pragma unroll
        for (int tau = 0; tau < 3; tau++) {
            #pragma unroll
            for (int kc = 0; kc < 4; kc++) {
                const float* wp = wb + (size_t)(tau * 128 + j) * HID + kc * 32 + quad * 8;
                f16x8 v;
                #pragma unroll
                for (int i = 0; i < 8; i++) v[i] = (_Float16)wp[i];
                bf[tau][kc] = v;
            }
        }
    }
    // ---- B-frags for w_ih (layers >= 1)
    f16x8 bi[3][4];
    if (l > 0) {
        const float* wb = w_ih_rest + (size_t)(l - 1) * G3 * HID;
        #pragma unroll
        for (int tau = 0; tau < 3; tau++) {
            #pragma unroll
            for (int kc = 0; kc < 4; kc++) {
                const float* wp = wb + (size_t)(tau * 128 + j) * HID + kc * 32 + quad * 8;
                f16x8 v;
                #pragma unroll
                for (int i = 0; i < 8; i++) v[i] = (_Float16)wp[i];
                bi[tau][kc] = v;
            }
        }
    }
    const float bhr = b_hh[l * G3 + j];
    const float bhz = b_hh[l * G3 + j + 128];
    const float bhn = b_hh[l * G3 + j + 256];
    float bir = 0.f, biz = 0.f, bin = 0.f;
    if (l > 0) {
        bir = b_ih[l * G3 + j];
        biz = b_ih[l * G3 + j + 128];
        bin = b_ih[l * G3 + j + 256];
    }

    // ---- zero h state ----
    for (int i = tid; i < 2 * 16 * 136; i += 512) ((_Float16*)hA)[i] = (_Float16)0.f;
    float vhp[4] = {0.f, 0.f, 0.f, 0.f};

    // ---- layer-0 gx pointers + preload t=0 ----
    const float* pR[4];
    float xr[4], xz[4], xn[4];
    if (l == 0) {
        #pragma unroll
        for (int r = 0; r < 4; r++) {
            pR[r] = gx0 + (size_t)(bm0 + quad * 4 + r) * SEQ * G3 + j;
            xr[r] = pR[r][0]; xz[r] = pR[r][128]; xn[r] = pR[r][256];
            pR[r] += G3;
        }
    }

    const _Float16* hprev = (l > 0) ? hmid + (size_t)((l - 1) * 4 + g) * SEQ * 2048 : (const _Float16*)nullptr;
    _Float16*       hpub  = (l < 4) ? hmid + (size_t)(l * 4 + g) * SEQ * 2048 : (_Float16*)nullptr;
    int*       dstflag = (l < 4) ? &flags[l * 4 + g] : (int*)nullptr;
    const int* srcflag = (l > 0) ? &flags[(l - 1) * 4 + g] : (const int*)nullptr;

    // ---- consumer: preload h_prev(0) A-frags ----
    f16x8 ap[4] = {};
    if (l > 0) {
        while (__hip_atomic_load(srcflag, __ATOMIC_ACQUIRE, __HIP_MEMORY_SCOPE_AGENT) < 1)
            __builtin_amdgcn_s_sleep(8);
        const _Float16* hp = hprev + n16 * 128 + quad * 8;
        #pragma unroll
        for (int kc = 0; kc < 4; kc++) ap[kc] = *(const f16x8*)(hp + kc * 32);
    }

    for (int t = 0; t < SEQ; t++) {
        __syncthreads();   // hA[t&1] ready; prior global h-stores drained (vmcnt0)
        if (l < 4 && t > 0 && tid == 0)
            __hip_atomic_store(dstflag, t, __ATOMIC_RELEASE, __HIP_MEMORY_SCOPE_AGENT);

        // early flag probe (checked at iter bottom -> latency overlapped)
        const int tn = t + 1;
        int fv = 0;
        if (l > 0 && tn < SEQ)
            fv = __hip_atomic_load(srcflag, __ATOMIC_ACQUIRE, __HIP_MEMORY_SCOPE_AGENT);

        // layer-0: issue gx(t+1) prefetch (in flight across the step)
        float nr[4], nz[4], nn[4];
        if (l == 0) {
            #pragma unroll
            for (int r = 0; r < 4; r++) {
                nr[r] = pR[r][0]; nz[r] = pR[r][128]; nn[r] = pR[r][256];
                pR[r] += G3;
            }
        }

        const int buf = t & 1;
        f16x8 af[4];
        #pragma unroll
        for (int kc = 0; kc < 4; kc++)
            af[kc] = *(const f16x8*)&hA[buf][n16][kc * 32 + quad * 8];

        // hh MFMAs
        f32x4 ah0 = {0.f,0.f,0.f,0.f}, ah1 = ah0, ah2 = ah0;
        #pragma unroll
        for (int kc = 0; kc < 4; kc++) {
            ah0 = __builtin_amdgcn_mfma_f32_16x16x32_f16(af[kc], bf[0][kc], ah0, 0, 0, 0);
            ah1 = __builtin_amdgcn_mfma_f32_16x16x32_f16(af[kc], bf[1][kc], ah1, 0, 0, 0);
            ah2 = __builtin_amdgcn_mfma_f32_16x16x32_f16(af[kc], bf[2][kc], ah2, 0, 0, 0);
        }
        // ih MFMAs (layers >= 1), uses ap loaded last iter
        f32x4 ai0 = {0.f,0.f,0.f,0.f}, ai1 = ai0, ai2 = ai0;
        if (l > 0) {
            #pragma unroll
            for (int kc = 0; kc < 4; kc++) {
                ai0 = __builtin_amdgcn_mfma_f32_16x16x32_f16(ap[kc], bi[0][kc], ai0, 0, 0, 0);
                ai1 = __builtin_amdgcn_mfma_f32_16x16x32_f16(ap[kc], bi[1][kc], ai1, 0, 0, 0);
                ai2 = __builtin_amdgcn_mfma_f32_16x16x32_f16(ap[kc], bi[2][kc], ai2, 0, 0, 0);
            }
        }

        // finalize: lane owns (m = quad*4+r, j) for all gates
        const int nbuf = buf ^ 1;
        #pragma unroll
        for (int r = 0; r < 4; r++) {
            const float gxr = (l == 0) ? xr[r] : (ai0[r] + bir);
            const float gxz = (l == 0) ? xz[r] : (ai1[r] + biz);
            const float gxn = (l == 0) ? xn[r] : (ai2[r] + bin);
            const float rg  = sigf(gxr + ah0[r] + bhr);
            const float zg  = sigf(gxz + ah1[r] + bhz);
            const float th  = tanh_fast(gxn + rg * (ah2[r] + bhn));
            const float hnew = fmaf(zg, vhp[r] - th, th);   // (1-z)n + z h
            vhp[r] = hnew;
            hA[nbuf][quad * 4 + r][j] = (_Float16)hnew;
            if (l < 4) hpub[(size_t)t * 2048 + (quad * 4 + r) * 128 + j] = (_Float16)hnew;
            if (l == 4 && t == SEQ - 1) hlast[(bm0 + quad * 4 + r) * 128 + j] = hnew;
        }

        if (l == 0) {
            #pragma unroll
            for (int r = 0; r < 4; r++) { xr[r] = nr[r]; xz[r] = nz[r]; xn[r] = nn[r]; }
        }

        // consumer: finish spin + prefetch h_prev(t+1) frags for next iter
        if (l > 0 && tn < SEQ) {
            while (fv < tn + 1) {
                __builtin_amdgcn_s_sleep(1);
                fv = __hip_atomic_load(srcflag, __ATOMIC_ACQUIRE, __HIP_MEMORY_SCOPE_AGENT);
            }
            const _Float16* hp = hprev + (size_t)tn * 2048 + n16 * 128 + quad * 8;
            #pragma unroll
            for (int kc = 0; kc < 4; kc++) ap[kc] = *(const f16x8*)(hp + kc * 32);
        }
    }

    __syncthreads();   // drain last h-stores
    if (l < 4 && tid == 0)
        __hip_atomic_store(dstflag, SEQ, __ATOMIC_RELEASE, __HIP_MEMORY_SCOPE_AGENT);
}

// ---------------------------------------------------------------------------
// fc: out[b][o] = hlast[b][:] . fc_w[o][:] + fc_b[o]
// ---------------------------------------------------------------------------
__global__ __launch_bounds__(128) void fc_kernel(const float* __restrict__ hlast,
                                                 const float* __restrict__ fc_w,
                                                 const float* __restrict__ fc_b,
                                                 float* __restrict__ out)
{
    const int b = blockIdx.x;
    const int o = threadIdx.x;
    if (o < 96) {
        const float* h = hlast + (size_t)b * HID;
        const float* wrow = fc_w + o * HID;
        float acc = fc_b[o];
        #pragma unroll 4
        for (int k = 0; k < HID; k++) acc = fmaf(h[k], wrow[k], acc);
        out[b * 96 + o] = acc;
    }
}

// ---------------------------------------------------------------------------
extern "C" void kernel_launch(void* const* d_in, const int* in_sizes, int n_in,
                              void* d_out, int out_size, void* d_ws, size_t ws_size,
                              hipStream_t stream)
{
    const float* x         = (const float*)d_in[0]; // [64][512][512]
    const float* w_ih0     = (const float*)d_in[1]; // [384][512]
    const float* w_ih_rest = (const float*)d_in[2]; // [4][384][128]
    const float* w_hh      = (const float*)d_in[3]; // [5][384][128]
    const float* b_ih      = (const float*)d_in[4]; // [5][384]
    const float* b_hh      = (const float*)d_in[5]; // [5][384]
    const float* fc_w      = (const float*)d_in[6]; // [96][128]
    const float* fc_b      = (const float*)d_in[7]; // [96]
    float* out = (float*)d_out;                     // [64][96]

    // workspace layout:
    //   [0,256)                    flags (16 ints, zeroed each launch)
    //   [256, +50331648)           gxbuf fp32 [64][512][384]
    //   [.., +33554432)            hmid  f16  [4][4][512][16][128]
    //   [.., +32768)               hlast fp32 [64][128]
    int*      flags = (int*)d_ws;
    float*    gxbuf = (float*)((char*)d_ws + 256);
    _Float16* hmid  = (_Float16*)((char*)d_ws + 256 + 50331648);
    float*    hlast = (float*)((char*)d_ws + 256 + 50331648 + 33554432);

    hipMemsetAsync(d_ws, 0, 256, stream);

    const dim3 gemmGrid(512, 6);
    gemm_gx<<<gemmGrid, 256, 0, stream>>>(x, w_ih0, b_ih, gxbuf, IN0);

    gru_pipeline<<<NLAY * 4, 512, 0, stream>>>(gxbuf, w_ih_rest, w_hh, b_ih, b_hh,
                                               hmid, hlast, flags);

    fc_kernel<<<BATCH, 128, 0, stream>>>(hlast, fc_w, fc_b, out);
}

// Round 10
// 1122.037 us; speedup vs baseline: 2.9744x; 1.6082x over previous
//
#include <hip/hip_runtime.h>
#include <hip/hip_bf16.h>

// Problem constants
#define BATCH   64
#define SEQ     512
#define IN0     512
#define HID     128
#define G3      384   // 3*HID
#define NLAY    5
#define CHUNK   8     // handoff granularity (one release/acquire per CHUNK steps)

typedef _Float16 f16x8 __attribute__((ext_vector_type(8)));
typedef float    f32x4 __attribute__((ext_vector_type(4)));

static __device__ __forceinline__ float sigf(float x) {
    return __builtin_amdgcn_rcpf(1.f + __expf(-x));
}
static __device__ __forceinline__ float tanh_fast(float x) {
    const float e = __expf(-2.f * fabsf(x));
    return copysignf((1.f - e) * __builtin_amdgcn_rcpf(1.f + e), x);
}

// ---------------------------------------------------------------------------
// gemm_gx: gx0[M=32768][384] = x[M][512] @ w_ih0[384][512]^T + b_ih0  (fp32)
// ---------------------------------------------------------------------------
__global__ __launch_bounds__(256) void gemm_gx(const float* __restrict__ A,
                                               const float* __restrict__ W,
                                               const float* __restrict__ bias,
                                               float* __restrict__ gx,
                                               int K)
{
    __shared__ __align__(16) float As[32][68];
    __shared__ __align__(16) float Bs[32][68];

    const int row0 = blockIdx.x * 64;
    const int col0 = blockIdx.y * 64;
    const int tid  = threadIdx.x;
    const int tx   = tid & 15;
    const int ty   = tid >> 4;
    const int r    = tid >> 2;
    const int kc   = (tid & 3) * 8;

    float acc[4][4] = {};

    for (int k0 = 0; k0 < K; k0 += 32) {
        {
            const float* Ap = A + (size_t)(row0 + r) * K + k0 + kc;
            float4 a0 = *(const float4*)(Ap);
            float4 a1 = *(const float4*)(Ap + 4);
            As[kc + 0][r] = a0.x; As[kc + 1][r] = a0.y; As[kc + 2][r] = a0.z; As[kc + 3][r] = a0.w;
            As[kc + 4][r] = a1.x; As[kc + 5][r] = a1.y; As[kc + 6][r] = a1.z; As[kc + 7][r] = a1.w;
        }
        {
            const float* Wp = W + (size_t)(col0 + r) * K + k0 + kc;
            float4 b0 = *(const float4*)(Wp);
            float4 b1 = *(const float4*)(Wp + 4);
            Bs[kc + 0][r] = b0.x; Bs[kc + 1][r] = b0.y; Bs[kc + 2][r] = b0.z; Bs[kc + 3][r] = b0.w;
            Bs[kc + 4][r] = b1.x; Bs[kc + 5][r] = b1.y; Bs[kc + 6][r] = b1.z; Bs[kc + 7][r] = b1.w;
        }
        __syncthreads();

        #pragma unroll
        for (int kk = 0; kk < 32; kk++) {
            float4 a = *(const float4*)&As[kk][ty * 4];
            float4 b = *(const float4*)&Bs[kk][tx * 4];
            acc[0][0] = fmaf(a.x, b.x, acc[0][0]); acc[0][1] = fmaf(a.x, b.y, acc[0][1]);
            acc[0][2] = fmaf(a.x, b.z, acc[0][2]); acc[0][3] = fmaf(a.x, b.w, acc[0][3]);
            acc[1][0] = fmaf(a.y, b.x, acc[1][0]); acc[1][1] = fmaf(a.y, b.y, acc[1][1]);
            acc[1][2] = fmaf(a.y, b.z, acc[1][2]); acc[1][3] = fmaf(a.y, b.w, acc[1][3]);
            acc[2][0] = fmaf(a.z, b.x, acc[2][0]); acc[2][1] = fmaf(a.z, b.y, acc[2][1]);
            acc[2][2] = fmaf(a.z, b.z, acc[2][2]); acc[2][3] = fmaf(a.z, b.w, acc[2][3]);
            acc[3][0] = fmaf(a.w, b.x, acc[3][0]); acc[3][1] = fmaf(a.w, b.y, acc[3][1]);
            acc[3][2] = fmaf(a.w, b.z, acc[3][2]); acc[3][3] = fmaf(a.w, b.w, acc[3][3]);
        }
        __syncthreads();
    }

    float bb[4];
    #pragma unroll
    for (int jj = 0; jj < 4; jj++) bb[jj] = bias[col0 + tx * 4 + jj];
    #pragma unroll
    for (int i = 0; i < 4; i++) {
        const int row = row0 + ty * 4 + i;
        float4 v;
        v.x = acc[i][0] + bb[0];
        v.y = acc[i][1] + bb[1];
        v.z = acc[i][2] + bb[2];
        v.w = acc[i][3] + bb[3];
        *(float4*)&gx[(size_t)row * G3 + col0 + tx * 4] = v;
    }
}

// ---------------------------------------------------------------------------
// gru_pipeline v4: identical to v3 (chunked acquire/release) with ONE fix:
// the consumer's h_prev fragment base was missing `quad*8` (dropped in the
// R8 refactor) — every quad read quad-0's k-slice. That, not the coherence
// protocol, caused both R8 and R9 failures (identical deterministic absmax).
// Protocol (unchanged, known-sound):
//   - producer: plain f16 stores; __syncthreads drains all waves (vmcnt0 ->
//     data complete in L2); tid0 RELEASE-stores flag once per CHUNK
//     (one buffer_wbl2 per 8 steps, amortized).
//   - consumer: RELAXED spin-polls (LLC reads, no inv); after success, ONE
//     ACQUIRE load (one buffer_inv per chunk); then plain vector loads —
//     every hmid address is read exactly once, so post-inv reads are fresh.
// ---------------------------------------------------------------------------
__global__ __launch_bounds__(512, 2) void gru_pipeline(
    const float* __restrict__ gx0,        // [64][512][384]
    const float* __restrict__ w_ih_rest,  // [4][384][128]
    const float* __restrict__ w_hh,       // [5][384][128]
    const float* __restrict__ b_ih,       // [5][384]
    const float* __restrict__ b_hh,       // [5][384]
    _Float16* __restrict__ hmid,          // [4][4][512][16][128]
    float* __restrict__ hlast,            // [64][128]
    int* __restrict__ flags)              // [16]
{
    const int l    = blockIdx.x >> 2;
    const int g    = blockIdx.x & 3;
    const int bm0  = g * 16;
    const int tid  = threadIdx.x;
    const int lane = tid & 63;
    const int wv   = tid >> 6;
    const int n16  = lane & 15;
    const int quad = lane >> 4;
    const int j    = wv * 16 + n16;       // hidden index this lane finalizes

    __shared__ __align__(16) _Float16 hA[2][16][136];

    // ---- B-frags for w_hh ----
    f16x8 bf[3][4];
    {
        const float* wb = w_hh + (size_t)l * G3 * HID;
        #pragma unroll
        for (int tau = 0; tau < 3; tau++)
            #pragma unroll
            for (int kc = 0; kc < 4; kc++) {
                const float* wp = wb + (size_t)(tau * 128 + j) * HID + kc * 32 + quad * 8;
                f16x8 v;
                #pragma unroll
                for (int i = 0; i < 8; i++) v[i] = (_Float16)wp[i];
                bf[tau][kc] = v;
            }
    }
    // ---- B-frags for w_ih (layers >= 1) ----
    f16x8 bi[3][4];
    if (l > 0) {
        const float* wb = w_ih_rest + (size_t)(l - 1) * G3 * HID;
        #pragma unroll
        for (int tau = 0; tau < 3; tau++)
            #pragma unroll
            for (int kc = 0; kc < 4; kc++) {
                const float* wp = wb + (size_t)(tau * 128 + j) * HID + kc * 32 + quad * 8;
                f16x8 v;
                #pragma unroll
                for (int i = 0; i < 8; i++) v[i] = (_Float16)wp[i];
                bi[tau][kc] = v;
            }
    }
    const float bhr = b_hh[l * G3 + j];
    const float bhz = b_hh[l * G3 + j + 128];
    const float bhn = b_hh[l * G3 + j + 256];
    float bir = 0.f, biz = 0.f, bin = 0.f;
    if (l > 0) {
        bir = b_ih[l * G3 + j];
        biz = b_ih[l * G3 + j + 128];
        bin = b_ih[l * G3 + j + 256];
    }

    // ---- zero h state ----
    for (int i = tid; i < 2 * 16 * 136; i += 512) ((_Float16*)hA)[i] = (_Float16)0.f;
    float vhp[4] = {0.f, 0.f, 0.f, 0.f};

    // ---- layer-0 gx pointers + preload t=0 ----
    const float* pR[4];
    float xr[4], xz[4], xn[4];
    if (l == 0) {
        #pragma unroll
        for (int r = 0; r < 4; r++) {
            pR[r] = gx0 + (size_t)(bm0 + quad * 4 + r) * SEQ * G3 + j;
            xr[r] = pR[r][0]; xz[r] = pR[r][128]; xn[r] = pR[r][256];
            pR[r] += G3;
        }
    }

    const _Float16* hprev = (l > 0) ? hmid + (size_t)((l - 1) * 4 + g) * SEQ * 2048 : (const _Float16*)nullptr;
    _Float16*       hpub  = (l < 4) ? hmid + (size_t)(l * 4 + g) * SEQ * 2048 : (_Float16*)nullptr;
    int*       dstflag = (l < 4) ? &flags[l * 4 + g] : (int*)nullptr;
    const int* srcflag = (l > 0) ? &flags[(l - 1) * 4 + g] : (const int*)nullptr;

    f16x8 ap[4];          // h_prev(t) A-frags for the current step
    // A-frag element i = h_prev[m = n16][k = kc*32 + quad*8 + i]
    const int hoff = n16 * 128 + quad * 8;   // <-- FIX: quad*8 restored (R8/R9 bug)

    for (int c = 0; c < SEQ / CHUNK; c++) {
        const int t0 = c * CHUNK;

        if (l > 0) {
            // once-per-chunk: relaxed spin, then ONE acquire load (buffer_inv)
            const int need = t0 + CHUNK;
            int v = __hip_atomic_load(srcflag, __ATOMIC_RELAXED, __HIP_MEMORY_SCOPE_AGENT);
            while (v < need) {
                __builtin_amdgcn_s_sleep(2);
                v = __hip_atomic_load(srcflag, __ATOMIC_RELAXED, __HIP_MEMORY_SCOPE_AGENT);
            }
            (void)__hip_atomic_load(srcflag, __ATOMIC_ACQUIRE, __HIP_MEMORY_SCOPE_AGENT);
            __asm__ volatile("" ::: "memory");
            // load ap for step t0 (plain vector loads, fresh post-inv)
            const _Float16* hp = hprev + (size_t)t0 * 2048 + hoff;
            #pragma unroll
            for (int kc = 0; kc < 4; kc++) ap[kc] = *(const f16x8*)(hp + kc * 32);
        }

        #pragma unroll
        for (int i = 0; i < CHUNK; i++) {
            const int t = t0 + i;
            __syncthreads();   // hA[t&1] ready; all waves' global stores drained (vmcnt0)

            // producer: publish chunk boundary with RELEASE (one wbl2 / chunk)
            if (l < 4 && i == 0 && c > 0 && tid == 0)
                __hip_atomic_store(dstflag, t0, __ATOMIC_RELEASE, __HIP_MEMORY_SCOPE_AGENT);

            // layer-0: issue gx(t+1) prefetch
            float nr[4], nz[4], nn[4];
            if (l == 0) {
                #pragma unroll
                for (int r = 0; r < 4; r++) {
                    nr[r] = pR[r][0]; nz[r] = pR[r][128]; nn[r] = pR[r][256];
                }
                if (t + 1 < SEQ) {
                    #pragma unroll
                    for (int r = 0; r < 4; r++) pR[r] += G3;
                }
            }

            const int buf = t & 1;
            f16x8 af[4];
            #pragma unroll
            for (int kc = 0; kc < 4; kc++)
                af[kc] = *(const f16x8*)&hA[buf][n16][kc * 32 + quad * 8];

            // hh MFMAs
            f32x4 ah0 = {0.f,0.f,0.f,0.f}, ah1 = ah0, ah2 = ah0;
            #pragma unroll
            for (int kc = 0; kc < 4; kc++) {
                ah0 = __builtin_amdgcn_mfma_f32_16x16x32_f16(af[kc], bf[0][kc], ah0, 0, 0, 0);
                ah1 = __builtin_amdgcn_mfma_f32_16x16x32_f16(af[kc], bf[1][kc], ah1, 0, 0, 0);
                ah2 = __builtin_amdgcn_mfma_f32_16x16x32_f16(af[kc], bf[2][kc], ah2, 0, 0, 0);
            }
            // ih MFMAs (layers >= 1)
            f32x4 ai0 = {0.f,0.f,0.f,0.f}, ai1 = ai0, ai2 = ai0;
            if (l > 0) {
                #pragma unroll
                for (int kc = 0; kc < 4; kc++) {
                    ai0 = __builtin_amdgcn_mfma_f32_16x16x32_f16(ap[kc], bi[0][kc], ai0, 0, 0, 0);
                    ai1 = __builtin_amdgcn_mfma_f32_16x16x32_f16(ap[kc], bi[1][kc], ai1, 0, 0, 0);
                    ai2 = __builtin_amdgcn_mfma_f32_16x16x32_f16(ap[kc], bi[2][kc], ai2, 0, 0, 0);
                }
            }

            // finalize: lane owns (m = quad*4+r, j) for all gates
            const int nbuf = buf ^ 1;
            #pragma unroll
            for (int r = 0; r < 4; r++) {
                const float gxr = (l == 0) ? xr[r] : (ai0[r] + bir);
                const float gxz = (l == 0) ? xz[r] : (ai1[r] + biz);
                const float gxn = (l == 0) ? xn[r] : (ai2[r] + bin);
                const float rg  = sigf(gxr + ah0[r] + bhr);
                const float zg  = sigf(gxz + ah1[r] + bhz);
                const float th  = tanh_fast(gxn + rg * (ah2[r] + bhn));
                const float hnew = fmaf(zg, vhp[r] - th, th);   // (1-z)n + z h
                vhp[r] = hnew;
                hA[nbuf][quad * 4 + r][j] = (_Float16)hnew;
                if (l < 4)
                    hpub[(size_t)t * 2048 + (quad * 4 + r) * 128 + j] = (_Float16)hnew;
                if (l == 4 && t == SEQ - 1)
                    hlast[(bm0 + quad * 4 + r) * 128 + j] = hnew;
            }

            if (l == 0) {
                #pragma unroll
                for (int r = 0; r < 4; r++) { xr[r] = nr[r]; xz[r] = nz[r]; xn[r] = nn[r]; }
            }

            // in-chunk prefetch of h_prev(t+1) (covered by this chunk's acquire)
            if (l > 0 && i < CHUNK - 1) {
                const _Float16* hp = hprev + (size_t)(t + 1) * 2048 + hoff;
                #pragma unroll
                for (int kc = 0; kc < 4; kc++) ap[kc] = *(const f16x8*)(hp + kc * 32);
            }
        }
    }

    __syncthreads();   // drain final chunk's stores
    if (l < 4 && tid == 0)
        __hip_atomic_store(dstflag, SEQ, __ATOMIC_RELEASE, __HIP_MEMORY_SCOPE_AGENT);
}

// ---------------------------------------------------------------------------
// fc: out[b][o] = hlast[b][:] . fc_w[o][:] + fc_b[o]
// ---------------------------------------------------------------------------
__global__ __launch_bounds__(128) void fc_kernel(const float* __restrict__ hlast,
                                                 const float* __restrict__ fc_w,
                                                 const float* __restrict__ fc_b,
                                                 float* __restrict__ out)
{
    const int b = blockIdx.x;
    const int o = threadIdx.x;
    if (o < 96) {
        const float* h = hlast + (size_t)b * HID;
        const float* wrow = fc_w + o * HID;
        float acc = fc_b[o];
        #pragma unroll 4
        for (int k = 0; k < HID; k++) acc = fmaf(h[k], wrow[k], acc);
        out[b * 96 + o] = acc;
    }
}

// ---------------------------------------------------------------------------
extern "C" void kernel_launch(void* const* d_in, const int* in_sizes, int n_in,
                              void* d_out, int out_size, void* d_ws, size_t ws_size,
                              hipStream_t stream)
{
    const float* x         = (const float*)d_in[0]; // [64][512][512]
    const float* w_ih0     = (const float*)d_in[1]; // [384][512]
    const float* w_ih_rest = (const float*)d_in[2]; // [4][384][128]
    const float* w_hh      = (const float*)d_in[3]; // [5][384][128]
    const float* b_ih      = (const float*)d_in[4]; // [5][384]
    const float* b_hh      = (const float*)d_in[5]; // [5][384]
    const float* fc_w      = (const float*)d_in[6]; // [96][128]
    const float* fc_b      = (const float*)d_in[7]; // [96]
    float* out = (float*)d_out;                     // [64][96]

    // workspace layout:
    //   [0,256)              flags (16 ints, zeroed each launch)
    //   [256, +50331648)     gxbuf fp32 [64][512][384]
    //   [.., +33554432)      hmid  f16  [4][4][512][16][128]
    //   [.., +32768)         hlast fp32 [64][128]
    int*      flags = (int*)d_ws;
    float*    gxbuf = (float*)((char*)d_ws + 256);
    _Float16* hmid  = (_Float16*)((char*)d_ws + 256 + 50331648);
    float*    hlast = (float*)((char*)d_ws + 256 + 50331648 + 33554432);

    hipMemsetAsync(d_ws, 0, 256, stream);

    const dim3 gemmGrid(512, 6);
    gemm_gx<<<gemmGrid, 256, 0, stream>>>(x, w_ih0, b_ih, gxbuf, IN0);

    gru_pipeline<<<NLAY * 4, 512, 0, stream>>>(gxbuf, w_ih_rest, w_hh, b_ih, b_hh,
                                               hmid, hlast, flags);

    fc_kernel<<<BATCH, 128, 0, stream>>>(hlast, fc_w, fc_b, out);
}

// Round 11
// 1106.981 us; speedup vs baseline: 3.0149x; 1.0136x over previous
//
#include <hip/hip_runtime.h>
#include <hip/hip_bf16.h>

// Problem constants
#define BATCH   64
#define SEQ     512
#define IN0     512
#define HID     128
#define G3      384   // 3*HID
#define NLAY    5
#define CHUNK   8     // handoff granularity (one release/acquire per CHUNK steps)

typedef _Float16 f16x8 __attribute__((ext_vector_type(8)));
typedef float    f32x4 __attribute__((ext_vector_type(4)));

static __device__ __forceinline__ float sigf(float x) {
    return __builtin_amdgcn_rcpf(1.f + __expf(-x));
}
static __device__ __forceinline__ float tanh_fast(float x) {
    const float e = __expf(-2.f * fabsf(x));
    return copysignf((1.f - e) * __builtin_amdgcn_rcpf(1.f + e), x);
}

// ---------------------------------------------------------------------------
// gemm_gx: gx0[M=32768][384] = x[M][512] @ w_ih0[384][512]^T + b_ih0  (fp32)
// ---------------------------------------------------------------------------
__global__ __launch_bounds__(256) void gemm_gx(const float* __restrict__ A,
                                               const float* __restrict__ W,
                                               const float* __restrict__ bias,
                                               float* __restrict__ gx,
                                               int K)
{
    __shared__ __align__(16) float As[32][68];
    __shared__ __align__(16) float Bs[32][68];

    const int row0 = blockIdx.x * 64;
    const int col0 = blockIdx.y * 64;
    const int tid  = threadIdx.x;
    const int tx   = tid & 15;
    const int ty   = tid >> 4;
    const int r    = tid >> 2;
    const int kc   = (tid & 3) * 8;

    float acc[4][4] = {};

    for (int k0 = 0; k0 < K; k0 += 32) {
        {
            const float* Ap = A + (size_t)(row0 + r) * K + k0 + kc;
            float4 a0 = *(const float4*)(Ap);
            float4 a1 = *(const float4*)(Ap + 4);
            As[kc + 0][r] = a0.x; As[kc + 1][r] = a0.y; As[kc + 2][r] = a0.z; As[kc + 3][r] = a0.w;
            As[kc + 4][r] = a1.x; As[kc + 5][r] = a1.y; As[kc + 6][r] = a1.z; As[kc + 7][r] = a1.w;
        }
        {
            const float* Wp = W + (size_t)(col0 + r) * K + k0 + kc;
            float4 b0 = *(const float4*)(Wp);
            float4 b1 = *(const float4*)(Wp + 4);
            Bs[kc + 0][r] = b0.x; Bs[kc + 1][r] = b0.y; Bs[kc + 2][r] = b0.z; Bs[kc + 3][r] = b0.w;
            Bs[kc + 4][r] = b1.x; Bs[kc + 5][r] = b1.y; Bs[kc + 6][r] = b1.z; Bs[kc + 7][r] = b1.w;
        }
        __syncthreads();

        #pragma unroll
        for (int kk = 0; kk < 32; kk++) {
            float4 a = *(const float4*)&As[kk][ty * 4];
            float4 b = *(const float4*)&Bs[kk][tx * 4];
            acc[0][0] = fmaf(a.x, b.x, acc[0][0]); acc[0][1] = fmaf(a.x, b.y, acc[0][1]);
            acc[0][2] = fmaf(a.x, b.z, acc[0][2]); acc[0][3] = fmaf(a.x, b.w, acc[0][3]);
            acc[1][0] = fmaf(a.y, b.x, acc[1][0]); acc[1][1] = fmaf(a.y, b.y, acc[1][1]);
            acc[1][2] = fmaf(a.y, b.z, acc[1][2]); acc[1][3] = fmaf(a.y, b.w, acc[1][3]);
            acc[2][0] = fmaf(a.z, b.x, acc[2][0]); acc[2][1] = fmaf(a.z, b.y, acc[2][1]);
            acc[2][2] = fmaf(a.z, b.z, acc[2][2]); acc[2][3] = fmaf(a.z, b.w, acc[2][3]);
            acc[3][0] = fmaf(a.w, b.x, acc[3][0]); acc[3][1] = fmaf(a.w, b.y, acc[3][1]);
            acc[3][2] = fmaf(a.w, b.z, acc[3][2]); acc[3][3] = fmaf(a.w, b.w, acc[3][3]);
        }
        __syncthreads();
    }

    float bb[4];
    #pragma unroll
    for (int jj = 0; jj < 4; jj++) bb[jj] = bias[col0 + tx * 4 + jj];
    #pragma unroll
    for (int i = 0; i < 4; i++) {
        const int row = row0 + ty * 4 + i;
        float4 v;
        v.x = acc[i][0] + bb[0];
        v.y = acc[i][1] + bb[1];
        v.z = acc[i][2] + bb[2];
        v.w = acc[i][3] + bb[3];
        *(float4*)&gx[(size_t)row * G3 + col0 + tx * 4] = v;
    }
}

// ---------------------------------------------------------------------------
// gru_pipeline v5 (over v4):
//  1. Per-step __syncthreads -> LDS flag barrier (ds_add + volatile LDS spin,
//     lgkmcnt only). Avoids the implicit `s_waitcnt vmcnt(0)` store-drain
//     every step (hpub stores complete lazily). One REAL __syncthreads per
//     chunk (before the RELEASE flag store) drains stores for the protocol.
//     DS ops complete in issue order per wave => arrive implies this wave's
//     hA writes visible; counter target += 8 waves/step (R5-proven pattern).
//  2. af ds_reads issued first, then ih MFMAs (register-only inputs) fill
//     the ~120cyc LDS latency, then hh MFMAs.
//  3. b_ih + b_hh folded into one per-gate constant.
// Handoff protocol unchanged from v4 (chunked RELEASE/ACQUIRE, R10-proven).
// ---------------------------------------------------------------------------
__global__ __launch_bounds__(512, 2) void gru_pipeline(
    const float* __restrict__ gx0,        // [64][512][384]
    const float* __restrict__ w_ih_rest,  // [4][384][128]
    const float* __restrict__ w_hh,       // [5][384][128]
    const float* __restrict__ b_ih,       // [5][384]
    const float* __restrict__ b_hh,       // [5][384]
    _Float16* __restrict__ hmid,          // [4][4][512][16][128]
    float* __restrict__ hlast,            // [64][128]
    int* __restrict__ flags)              // [16]
{
    const int l    = blockIdx.x >> 2;
    const int g    = blockIdx.x & 3;
    const int bm0  = g * 16;
    const int tid  = threadIdx.x;
    const int lane = tid & 63;
    const int n16  = lane & 15;
    const int quad = lane >> 4;
    const int wv   = tid >> 6;
    const int j    = wv * 16 + n16;       // hidden index this lane finalizes

    __shared__ __align__(16) _Float16 hA[2][16][136];
    __shared__ int barcnt;

    // ---- B-frags for w_hh ----
    f16x8 bf[3][4];
    {
        const float* wb = w_hh + (size_t)l * G3 * HID;
        #pragma unroll
        for (int tau = 0; tau < 3; tau++)
            #pragma unroll
            for (int kc = 0; kc < 4; kc++) {
                const float* wp = wb + (size_t)(tau * 128 + j) * HID + kc * 32 + quad * 8;
                f16x8 v;
                #pragma unroll
                for (int i = 0; i < 8; i++) v[i] = (_Float16)wp[i];
                bf[tau][kc] = v;
            }
    }
    // ---- B-frags for w_ih (layers >= 1) ----
    f16x8 bi[3][4];
    if (l > 0) {
        const float* wb = w_ih_rest + (size_t)(l - 1) * G3 * HID;
        #pragma unroll
        for (int tau = 0; tau < 3; tau++)
            #pragma unroll
            for (int kc = 0; kc < 4; kc++) {
                const float* wp = wb + (size_t)(tau * 128 + j) * HID + kc * 32 + quad * 8;
                f16x8 v;
                #pragma unroll
                for (int i = 0; i < 8; i++) v[i] = (_Float16)wp[i];
                bi[tau][kc] = v;
            }
    }
    // folded gate biases (gx0 already contains b_ih for layer 0)
    const float bcr = b_hh[l * G3 + j]       + ((l > 0) ? b_ih[l * G3 + j]       : 0.f);
    const float bcz = b_hh[l * G3 + j + 128] + ((l > 0) ? b_ih[l * G3 + j + 128] : 0.f);
    const float bcn = b_hh[l * G3 + j + 256];                      // n-gate: b_hh inside r*(...)
    const float bxn = (l > 0) ? b_ih[l * G3 + j + 256] : 0.f;      // n-gate: b_ih outside

    // ---- zero h state ----
    for (int i = tid; i < 2 * 16 * 136; i += 512) ((_Float16*)hA)[i] = (_Float16)0.f;
    float vhp[4] = {0.f, 0.f, 0.f, 0.f};
    if (tid == 0) barcnt = 0;

    // ---- layer-0 gx pointers + preload t=0 ----
    const float* pR[4];
    float xr[4], xz[4], xn[4];
    if (l == 0) {
        #pragma unroll
        for (int r = 0; r < 4; r++) {
            pR[r] = gx0 + (size_t)(bm0 + quad * 4 + r) * SEQ * G3 + j;
            xr[r] = pR[r][0]; xz[r] = pR[r][128]; xn[r] = pR[r][256];
            pR[r] += G3;
        }
    }

    const _Float16* hprev = (l > 0) ? hmid + (size_t)((l - 1) * 4 + g) * SEQ * 2048 : (const _Float16*)nullptr;
    _Float16*       hpub  = (l < 4) ? hmid + (size_t)(l * 4 + g) * SEQ * 2048 : (_Float16*)nullptr;
    int*       dstflag = (l < 4) ? &flags[l * 4 + g] : (int*)nullptr;
    const int* srcflag = (l > 0) ? &flags[(l - 1) * 4 + g] : (const int*)nullptr;

    _Float16* hw = (l < 4) ? hpub + quad * 4 * 128 + j : (_Float16*)nullptr;  // walks by 2048/step

    f16x8 ap[4];                             // h_prev(t) A-frags
    const int hoff = n16 * 128 + quad * 8;   // A-frag base (m=n16, k=quad*8)

    __syncthreads();   // hA zero + barcnt visible

    volatile int* bc = &barcnt;
    int btarget = 0;

    for (int c = 0; c < SEQ / CHUNK; c++) {
        const int t0 = c * CHUNK;

        if (l > 0) {
            // once-per-chunk: relaxed spin, then ONE acquire load (buffer_inv)
            const int need = t0 + CHUNK;
            int v = __hip_atomic_load(srcflag, __ATOMIC_RELAXED, __HIP_MEMORY_SCOPE_AGENT);
            while (v < need) {
                __builtin_amdgcn_s_sleep(2);
                v = __hip_atomic_load(srcflag, __ATOMIC_RELAXED, __HIP_MEMORY_SCOPE_AGENT);
            }
            (void)__hip_atomic_load(srcflag, __ATOMIC_ACQUIRE, __HIP_MEMORY_SCOPE_AGENT);
            __asm__ volatile("" ::: "memory");
            const _Float16* hp = hprev + (size_t)t0 * 2048 + hoff;
            #pragma unroll
            for (int kc = 0; kc < 4; kc++) ap[kc] = *(const f16x8*)(hp + kc * 32);
        }

        #pragma unroll
        for (int i = 0; i < CHUNK; i++) {
            const int t = t0 + i;

            // ---- LDS flag barrier: no vmcnt drain (stores stay in flight) ----
            __asm__ volatile("" ::: "memory");
            if (lane == 0) atomicAdd(&barcnt, 1);
            btarget += 8;
            while (*bc < btarget) { __builtin_amdgcn_s_sleep(1); }
            __asm__ volatile("" ::: "memory");

            const int buf = t & 1;
            // issue af LDS reads first (latency overlapped by ih MFMAs below)
            f16x8 af[4];
            #pragma unroll
            for (int kc = 0; kc < 4; kc++)
                af[kc] = *(const f16x8*)&hA[buf][n16][kc * 32 + quad * 8];

            // ih MFMAs (register inputs, no LDS dependency) — issue first
            f32x4 ai0 = {0.f,0.f,0.f,0.f}, ai1 = ai0, ai2 = ai0;
            if (l > 0) {
                #pragma unroll
                for (int kc = 0; kc < 4; kc++) {
                    ai0 = __builtin_amdgcn_mfma_f32_16x16x32_f16(ap[kc], bi[0][kc], ai0, 0, 0, 0);
                    ai1 = __builtin_amdgcn_mfma_f32_16x16x32_f16(ap[kc], bi[1][kc], ai1, 0, 0, 0);
                    ai2 = __builtin_amdgcn_mfma_f32_16x16x32_f16(ap[kc], bi[2][kc], ai2, 0, 0, 0);
                }
            }
            // layer-0: issue gx(t+1) prefetch
            float nr[4], nz[4], nn[4];
            if (l == 0) {
                #pragma unroll
                for (int r = 0; r < 4; r++) {
                    nr[r] = pR[r][0]; nz[r] = pR[r][128]; nn[r] = pR[r][256];
                }
                if (t + 1 < SEQ) {
                    #pragma unroll
                    for (int r = 0; r < 4; r++) pR[r] += G3;
                }
            }

            // hh MFMAs
            f32x4 ah0 = {0.f,0.f,0.f,0.f}, ah1 = ah0, ah2 = ah0;
            #pragma unroll
            for (int kc = 0; kc < 4; kc++) {
                ah0 = __builtin_amdgcn_mfma_f32_16x16x32_f16(af[kc], bf[0][kc], ah0, 0, 0, 0);
                ah1 = __builtin_amdgcn_mfma_f32_16x16x32_f16(af[kc], bf[1][kc], ah1, 0, 0, 0);
                ah2 = __builtin_amdgcn_mfma_f32_16x16x32_f16(af[kc], bf[2][kc], ah2, 0, 0, 0);
            }

            // finalize: lane owns (m = quad*4+r, j) for all gates
            const int nbuf = buf ^ 1;
            #pragma unroll
            for (int r = 0; r < 4; r++) {
                const float sxr = (l == 0) ? xr[r] : ai0[r];
                const float sxz = (l == 0) ? xz[r] : ai1[r];
                const float sxn = ((l == 0) ? xn[r] : ai2[r]) + bxn;
                const float rg  = sigf(sxr + ah0[r] + bcr);
                const float zg  = sigf(sxz + ah1[r] + bcz);
                const float th  = tanh_fast(sxn + rg * (ah2[r] + bcn));
                const float hnew = fmaf(zg, vhp[r] - th, th);   // (1-z)n + z h
                vhp[r] = hnew;
                hA[nbuf][quad * 4 + r][j] = (_Float16)hnew;
                if (l < 4) hw[r * 128] = (_Float16)hnew;        // drains at chunk-end syncthreads
                if (l == 4 && t == SEQ - 1)
                    hlast[(bm0 + quad * 4 + r) * 128 + j] = hnew;
            }
            if (l < 4) hw += 2048;

            if (l == 0) {
                #pragma unroll
                for (int r = 0; r < 4; r++) { xr[r] = nr[r]; xz[r] = nz[r]; xn[r] = nn[r]; }
            }

            // in-chunk prefetch of h_prev(t+1) (covered by this chunk's acquire)
            if (l > 0 && i < CHUNK - 1) {
                const _Float16* hp = hprev + (size_t)(t + 1) * 2048 + hoff;
                #pragma unroll
                for (int kc = 0; kc < 4; kc++) ap[kc] = *(const f16x8*)(hp + kc * 32);
            }
        }

        // ---- chunk boundary: REAL barrier (drains hpub stores), then RELEASE
        __syncthreads();
        if (l < 4 && tid == 0)
            __hip_atomic_store(dstflag, t0 + CHUNK, __ATOMIC_RELEASE, __HIP_MEMORY_SCOPE_AGENT);
    }
}

// ---------------------------------------------------------------------------
// fc: out[b][o] = hlast[b][:] . fc_w[o][:] + fc_b[o]
// ---------------------------------------------------------------------------
__global__ __launch_bounds__(128) void fc_kernel(const float* __restrict__ hlast,
                                                 const float* __restrict__ fc_w,
                                                 const float* __restrict__ fc_b,
                                                 float* __restrict__ out)
{
    const int b = blockIdx.x;
    const int o = threadIdx.x;
    if (o < 96) {
        const float* h = hlast + (size_t)b * HID;
        const float* wrow = fc_w + o * HID;
        float acc = fc_b[o];
        #pragma unroll 4
        for (int k = 0; k < HID; k++) acc = fmaf(h[k], wrow[k], acc);
        out[b * 96 + o] = acc;
    }
}

// ---------------------------------------------------------------------------
extern "C" void kernel_launch(void* const* d_in, const int* in_sizes, int n_in,
                              void* d_out, int out_size, void* d_ws, size_t ws_size,
                              hipStream_t stream)
{
    const float* x         = (const float*)d_in[0]; // [64][512][512]
    const float* w_ih0     = (const float*)d_in[1]; // [384][512]
    const float* w_ih_rest = (const float*)d_in[2]; // [4][384][128]
    const float* w_hh      = (const float*)d_in[3]; // [5][384][128]
    const float* b_ih      = (const float*)d_in[4]; // [5][384]
    const float* b_hh      = (const float*)d_in[5]; // [5][384]
    const float* fc_w      = (const float*)d_in[6]; // [96][128]
    const float* fc_b      = (const float*)d_in[7]; // [96]
    float* out = (float*)d_out;                     // [64][96]

    // workspace layout:
    //   [0,256)              flags (16 ints, zeroed each launch)
    //   [256, +50331648)     gxbuf fp32 [64][512][384]
    //   [.., +33554432)      hmid  f16  [4][4][512][16][128]
    //   [.., +32768)         hlast fp32 [64][128]
    int*      flags = (int*)d_ws;
    float*    gxbuf = (float*)((char*)d_ws + 256);
    _Float16* hmid  = (_Float16*)((char*)d_ws + 256 + 50331648);
    float*    hlast = (float*)((char*)d_ws + 256 + 50331648 + 33554432);

    hipMemsetAsync(d_ws, 0, 256, stream);

    const dim3 gemmGrid(512, 6);
    gemm_gx<<<gemmGrid, 256, 0, stream>>>(x, w_ih0, b_ih, gxbuf, IN0);

    gru_pipeline<<<NLAY * 4, 512, 0, stream>>>(gxbuf, w_ih_rest, w_hh, b_ih, b_hh,
                                               hmid, hlast, flags);

    fc_kernel<<<BATCH, 128, 0, stream>>>(hlast, fc_w, fc_b, out);
}